// Round 12
// baseline (437.470 us; speedup 1.0000x reference)
//
#include <hip/hip_runtime.h>
#include <math.h>

#define B_     16
#define C_     64
#define HW_    512
#define KS_    15
#define HALO   7
#define PROW   528      // padded row: 8 + 512 + 8 floats (16B-aligned)
#define PADOFF 2048     // float offset of padded image inside ws (8 KB coefs)
#define YSEG   128      // rows per wave
#define NSEG   4        // 512 / YSEG

typedef float vf4 __attribute__((ext_vector_type(4)));

// ---------------------------------------------------------------------------
// coefs[c*32 + i]      = F2*sinc(pi*F2*(i-7))*hamming[i]   (A)
// coefs[c*32 + 16 + i] = F1*sinc(pi*F1*(i-7))*hamming[i]   (B)
// Palindromic (cf[k]==cf[14-k], R10-proven); conv kernel reads k=0..7 only.
// ---------------------------------------------------------------------------
__global__ void make_filters(const float* __restrict__ f1,
                             const float* __restrict__ band,
                             float* __restrict__ coefs) {
    int c = threadIdx.x;
    if (c >= C_) return;
    float F1 = f1[c];
    float F2 = F1 + fabsf(band[c]);
    const float PI = 3.14159265358979323846f;
    #pragma unroll
    for (int i = 0; i < KS_; ++i) {
        float h = 0.54f - 0.46f * cosf((2.0f * PI / 14.0f) * (float)i);
        float y1, y2;
        if (i == HALO) {
            y1 = 1.0f; y2 = 1.0f;
        } else {
            float t  = (float)(i - HALO);
            float a1 = PI * F1 * t;
            float a2 = PI * F2 * t;
            y1 = sinf(a1) / a1;
            y2 = sinf(a2) / a2;
        }
        coefs[c * 32 + i]      = F2 * y2 * h;
        coefs[c * 32 + 16 + i] = F1 * y1 * h;
    }
}

// ---------------------------------------------------------------------------
// Column-padded input copy (R5/R8-proven): xp[row*528 + gx + 8] = x[row*512+gx]
// ---------------------------------------------------------------------------
__global__ void pad_copy(const float* __restrict__ x, float* __restrict__ xp) {
    int t   = blockIdx.x * 256 + threadIdx.x;   // 8192 rows * 132 quads
    int pc4 = t % 132;
    int row = t / 132;
    const float* src = x + (size_t)row * HW_;
    int gx0 = pc4 * 4 - 8;
    float v[4];
    #pragma unroll
    for (int e = 0; e < 4; ++e) {
        int gx = gx0 + e;
        v[e] = ((unsigned)gx < (unsigned)HW_) ? src[gx] : 0.0f;
    }
    *(vf4*)(xp + (size_t)row * PROW + pc4 * 4) = *(const vf4*)v;
}

// ---------------------------------------------------------------------------
// Fused single-pass separable conv, 4 cols/thread, no LDS.
// R11-proven structure (17-slot delay line, 3-phase static indexing,
// symmetric hconv) with ONE change: consume-then-prefetch. Each iteration:
//   (1) hconv reduces w[20] (row y) into hA/hB           (~92 ops)
//   (2) issue row y+1's 5 dwordx4 loads into w (or zero)  -> latency
//       covered by (3) + next iter's (1), no double buffer
//   (3) vconv taps into static slots, store row y-7, shift per group of 3
// ---------------------------------------------------------------------------
__global__ __launch_bounds__(64, 4)
void sinc_u3p(const float* __restrict__ xpad,
              const float* __restrict__ coefs,
              float* __restrict__ out) {
    const int lane = threadIdx.x;              // 64 threads = 1 wave
    const int bid  = blockIdx.x;
    const int ch   = bid & 63;                 // channel fastest (L2 sharing)
    const int xh   = (bid >> 6) & 1;
    const int seg  = (bid >> 7) & (NSEG - 1);
    const int b    = bid >> 9;
    const int sx   = xh * 256;
    const int y0   = seg * YSEG;
    const int c0   = sx + 4 * lane;

    // wave-uniform half-coefficients -> SGPR (palindrome: cf[k]=cf[14-k])
    float cA[8], cB[8];
    #pragma unroll
    for (int i = 0; i < 8; ++i) {
        cA[i] = __uint_as_float(__builtin_amdgcn_readfirstlane(
                    __float_as_uint(coefs[ch * 32 + i])));
        cB[i] = __uint_as_float(__builtin_amdgcn_readfirstlane(
                    __float_as_uint(coefs[ch * 32 + 16 + i])));
    }

    const float* xw = xpad + (size_t)b * HW_ * PROW + c0;  // + y*PROW per row
    float* ob = out + ((size_t)(b * C_ + ch) * HW_) * HW_ + c0;

    float acc[17][4];
    #pragma unroll
    for (int j = 0; j < 17; ++j)
        #pragma unroll
        for (int c = 0; c < 4; ++c) acc[j][c] = 0.0f;

    // window registers + prologue load of the first row (y0-7)
    float w[20] __attribute__((aligned(16)));
    {
        const int y = y0 - HALO;
        if ((unsigned)y < (unsigned)HW_) {
            const float* p = xw + (size_t)y * PROW;
            #pragma unroll
            for (int m = 0; m < 5; ++m)
                *(vf4*)(w + 4 * m) = *(const vf4*)(p + 4 * m);
        } else {
            #pragma unroll
            for (int m = 0; m < 20; ++m) w[m] = 0.0f;
        }
    }

    #pragma unroll 1
    for (int g = 0; g < 48; ++g) {
        #pragma unroll
        for (int u = 0; u < 3; ++u) {
            const int r = g * 3 + u;           // iteration index 0..143
            const int y = y0 - HALO + r;       // input row held in w

            // (1) symmetric hconv: h(c0+c) = cf[7]*w[c+8] + sum cf[k]*(w+w)
            float hA[4], hB[4];
            #pragma unroll
            for (int c = 0; c < 4; ++c) {
                hA[c] = cA[7] * w[c + 8];
                hB[c] = cB[7] * w[c + 8];
            }
            #pragma unroll
            for (int k = 0; k < 7; ++k) {
                #pragma unroll
                for (int c = 0; c < 4; ++c) {
                    float s = w[c + k + 1] + w[c + 15 - k];
                    hA[c] = fmaf(cA[k], s, hA[c]);
                    hB[c] = fmaf(cB[k], s, hB[c]);
                }
            }

            // (2) prefetch next row (y+1) into w; consumed next iteration
            {
                const int yn = y + 1;
                if ((unsigned)yn < (unsigned)HW_) {
                    const float* p = xw + (size_t)yn * PROW;
                    #pragma unroll
                    for (int m = 0; m < 5; ++m)
                        *(vf4*)(w + 4 * m) = *(const vf4*)(p + 4 * m);
                } else {
                    #pragma unroll
                    for (int m = 0; m < 20; ++m) w[m] = 0.0f;
                }
            }

            // (3a) tap j=14: MUL-init phys slot u+14 (row y+7 restart, cf[0])
            #pragma unroll
            for (int c = 0; c < 4; ++c)
                acc[u + 14][c] = fmaf(-cB[0], hB[c], cA[0] * hA[c]);
            // (3b) taps j=0..13: phys slot u+j += cf[14-j]*h (palindrome)
            #pragma unroll
            for (int j = 0; j < 14; ++j) {
                const int m  = 14 - j;
                const int ci = (m < 8) ? m : 14 - m;
                #pragma unroll
                for (int c = 0; c < 4; ++c) {
                    acc[u + j][c] = fmaf( cA[ci], hA[c], acc[u + j][c]);
                    acc[u + j][c] = fmaf(-cB[ci], hB[c], acc[u + j][c]);
                }
            }
            // (3c) store completed output row yo = y-7 from phys slot u
            const int rel = r - 14;
            if ((unsigned)rel < (unsigned)YSEG) {
                vf4 st = {acc[u][0], acc[u][1], acc[u][2], acc[u][3]};
                __builtin_nontemporal_store(st,
                    (vf4*)(ob + (size_t)(y0 + rel) * HW_));
            }
        }
        // shift delay line by 3 (14 live slots)
        #pragma unroll
        for (int p = 0; p < 14; ++p)
            #pragma unroll
            for (int c = 0; c < 4; ++c)
                acc[p][c] = acc[p + 3][c];
    }
}

extern "C" void kernel_launch(void* const* d_in, const int* in_sizes, int n_in,
                              void* d_out, int out_size, void* d_ws, size_t ws_size,
                              hipStream_t stream) {
    const float* x    = (const float*)d_in[0];
    const float* f1   = (const float*)d_in[1];
    const float* band = (const float*)d_in[2];
    float* ws   = (float*)d_ws;
    float* outp = (float*)d_out;
    float* xp   = ws + PADOFF;

    hipLaunchKernelGGL(make_filters, dim3(1), dim3(64), 0, stream,
                       f1, band, ws);
    hipLaunchKernelGGL(pad_copy, dim3(4224), dim3(256), 0, stream, x, xp);

    const int nblocks = B_ * C_ * 2 * NSEG;    // 8192 one-wave blocks
    hipLaunchKernelGGL(sinc_u3p, dim3(nblocks), dim3(64), 0, stream,
                       xp, ws, outp);
}

// Round 13
// 413.922 us; speedup vs baseline: 1.0569x; 1.0569x over previous
//
#include <hip/hip_runtime.h>
#include <math.h>

#define B_     16
#define C_     64
#define HW_    512
#define KS_    15
#define HALO   7
#define PROW   528      // padded row: 8 + 512 + 8 floats (16B-aligned)
#define PADOFF 2048     // float offset of padded image inside ws (8 KB coefs)
#define YSEG   256      // rows per wave
#define NSEG   2        // 512 / YSEG
#define NPH    5        // unroll phases per group
#define NITER  270      // YSEG + 14, = 54 * NPH exactly

typedef float vf4 __attribute__((ext_vector_type(4)));

// ---------------------------------------------------------------------------
// coefs[c*32 + i]      = F2*sinc(pi*F2*(i-7))*hamming[i]   (A)
// coefs[c*32 + 16 + i] = F1*sinc(pi*F1*(i-7))*hamming[i]   (B)
// Palindromic (cf[k]==cf[14-k], R10-proven); conv kernel reads k=0..7 only.
// ---------------------------------------------------------------------------
__global__ void make_filters(const float* __restrict__ f1,
                             const float* __restrict__ band,
                             float* __restrict__ coefs) {
    int c = threadIdx.x;
    if (c >= C_) return;
    float F1 = f1[c];
    float F2 = F1 + fabsf(band[c]);
    const float PI = 3.14159265358979323846f;
    #pragma unroll
    for (int i = 0; i < KS_; ++i) {
        float h = 0.54f - 0.46f * cosf((2.0f * PI / 14.0f) * (float)i);
        float y1, y2;
        if (i == HALO) {
            y1 = 1.0f; y2 = 1.0f;
        } else {
            float t  = (float)(i - HALO);
            float a1 = PI * F1 * t;
            float a2 = PI * F2 * t;
            y1 = sinf(a1) / a1;
            y2 = sinf(a2) / a2;
        }
        coefs[c * 32 + i]      = F2 * y2 * h;
        coefs[c * 32 + 16 + i] = F1 * y1 * h;
    }
}

// ---------------------------------------------------------------------------
// Column-padded input copy (R5/R8-proven): xp[row*528 + gx + 8] = x[row*512+gx]
// ---------------------------------------------------------------------------
__global__ void pad_copy(const float* __restrict__ x, float* __restrict__ xp) {
    int t   = blockIdx.x * 256 + threadIdx.x;   // 8192 rows * 132 quads
    int pc4 = t % 132;
    int row = t / 132;
    const float* src = x + (size_t)row * HW_;
    int gx0 = pc4 * 4 - 8;
    float v[4];
    #pragma unroll
    for (int e = 0; e < 4; ++e) {
        int gx = gx0 + e;
        v[e] = ((unsigned)gx < (unsigned)HW_) ? src[gx] : 0.0f;
    }
    *(vf4*)(xp + (size_t)row * PROW + pc4 * 4) = *(const vf4*)v;
}

// ---------------------------------------------------------------------------
// Fused single-pass separable conv, 4 cols/thread, no LDS.
// R11-proven structure with two parameter changes:
//   - YSEG 256 (halo overhead 14/270 vs 16/144 of iterations)
//   - 5-phase static unroll, 19 slots (shift is fixed 56 movs/group ->
//     11.2 movs/row vs 18.7)
// Phase u (0..4), input row y = y0-7+r, r = 5g+u, loads at iteration top
// (R11-proven order; R12's prefetch reorder regressed via regalloc):
//   tap j=0..13: phys slot u+j += cf[14-j]*h   (static indices)
//   tap j=14:    phys slot u+14 = MUL-init with cf[0] (row restart)
//   store phys slot u -> output row y-7 (guarded to [y0, y0+YSEG))
// Group end: shift acc[p] = acc[p+5], p=0..13.
// OOB rows run with w=0 (MUL-init still executes -> correct restart).
// ---------------------------------------------------------------------------
__global__ __launch_bounds__(64, 4)
void sinc_u5(const float* __restrict__ xpad,
             const float* __restrict__ coefs,
             float* __restrict__ out) {
    const int lane = threadIdx.x;              // 64 threads = 1 wave
    const int bid  = blockIdx.x;
    const int ch   = bid & 63;                 // channel fastest (L2 sharing)
    const int xh   = (bid >> 6) & 1;
    const int seg  = (bid >> 7) & (NSEG - 1);
    const int b    = bid >> 8;
    const int sx   = xh * 256;
    const int y0   = seg * YSEG;
    const int c0   = sx + 4 * lane;

    // wave-uniform half-coefficients -> SGPR (palindrome: cf[k]=cf[14-k])
    float cA[8], cB[8];
    #pragma unroll
    for (int i = 0; i < 8; ++i) {
        cA[i] = __uint_as_float(__builtin_amdgcn_readfirstlane(
                    __float_as_uint(coefs[ch * 32 + i])));
        cB[i] = __uint_as_float(__builtin_amdgcn_readfirstlane(
                    __float_as_uint(coefs[ch * 32 + 16 + i])));
    }

    const float* xw = xpad + (size_t)b * HW_ * PROW + c0;  // + y*PROW per row
    float* ob = out + ((size_t)(b * C_ + ch) * HW_) * HW_ + c0;

    float acc[NPH + 14][4];                    // 19 slots
    #pragma unroll
    for (int j = 0; j < NPH + 14; ++j)
        #pragma unroll
        for (int c = 0; c < 4; ++c) acc[j][c] = 0.0f;

    #pragma unroll 1
    for (int g = 0; g < NITER / NPH; ++g) {    // 54 groups
        #pragma unroll
        for (int u = 0; u < NPH; ++u) {
            const int r = g * NPH + u;         // iteration index 0..269
            const int y = y0 - HALO + r;       // input row

            // load 20-float window (5x aligned dwordx4), zero when OOB
            float w[20] __attribute__((aligned(16)));
            if ((unsigned)y < (unsigned)HW_) {
                const float* p = xw + (size_t)y * PROW;
                #pragma unroll
                for (int m = 0; m < 5; ++m)
                    *(vf4*)(w + 4 * m) = *(const vf4*)(p + 4 * m);
            } else {
                #pragma unroll
                for (int m = 0; m < 20; ++m) w[m] = 0.0f;
            }

            // symmetric hconv: h(c0+c) = cf[7]*w[c+8] + sum cf[k]*(w+w)
            float hA[4], hB[4];
            #pragma unroll
            for (int c = 0; c < 4; ++c) {
                hA[c] = cA[7] * w[c + 8];
                hB[c] = cB[7] * w[c + 8];
            }
            #pragma unroll
            for (int k = 0; k < 7; ++k) {
                #pragma unroll
                for (int c = 0; c < 4; ++c) {
                    float s = w[c + k + 1] + w[c + 15 - k];
                    hA[c] = fmaf(cA[k], s, hA[c]);
                    hB[c] = fmaf(cB[k], s, hB[c]);
                }
            }

            // tap j=14: MUL-init phys slot u+14 (row y+7 restart, cf[0])
            #pragma unroll
            for (int c = 0; c < 4; ++c)
                acc[u + 14][c] = fmaf(-cB[0], hB[c], cA[0] * hA[c]);
            // taps j=0..13: phys slot u+j += cf[14-j]*h (palindrome index)
            #pragma unroll
            for (int j = 0; j < 14; ++j) {
                const int m  = 14 - j;
                const int ci = (m < 8) ? m : 14 - m;
                #pragma unroll
                for (int c = 0; c < 4; ++c) {
                    acc[u + j][c] = fmaf( cA[ci], hA[c], acc[u + j][c]);
                    acc[u + j][c] = fmaf(-cB[ci], hB[c], acc[u + j][c]);
                }
            }
            // store completed output row yo = y-7 from phys slot u
            const int rel = r - 14;
            if ((unsigned)rel < (unsigned)YSEG) {
                vf4 st = {acc[u][0], acc[u][1], acc[u][2], acc[u][3]};
                __builtin_nontemporal_store(st,
                    (vf4*)(ob + (size_t)(y0 + rel) * HW_));
            }
        }
        // shift delay line by NPH (14 live slots, 56 movs per 5 rows)
        #pragma unroll
        for (int p = 0; p < 14; ++p)
            #pragma unroll
            for (int c = 0; c < 4; ++c)
                acc[p][c] = acc[p + NPH][c];
    }
}

extern "C" void kernel_launch(void* const* d_in, const int* in_sizes, int n_in,
                              void* d_out, int out_size, void* d_ws, size_t ws_size,
                              hipStream_t stream) {
    const float* x    = (const float*)d_in[0];
    const float* f1   = (const float*)d_in[1];
    const float* band = (const float*)d_in[2];
    float* ws   = (float*)d_ws;
    float* outp = (float*)d_out;
    float* xp   = ws + PADOFF;

    hipLaunchKernelGGL(make_filters, dim3(1), dim3(64), 0, stream,
                       f1, band, ws);
    hipLaunchKernelGGL(pad_copy, dim3(4224), dim3(256), 0, stream, x, xp);

    const int nblocks = B_ * C_ * 2 * NSEG;    // 4096 one-wave blocks
    hipLaunchKernelGGL(sinc_u5, dim3(nblocks), dim3(64), 0, stream,
                       xp, ws, outp);
}